// Round 6
// baseline (185.014 us; speedup 1.0000x reference)
//
#include <hip/hip_runtime.h>
#include <stdint.h>

// B=2, T=2048, C=1024, H=16, D=64
#define SEQ   2048
#define EMBD  1024
#define M_ROWS 4096

typedef unsigned short u16;
typedef unsigned int u32;
typedef __attribute__((ext_vector_type(8))) short bf16x8;
typedef __attribute__((ext_vector_type(4))) float f32x4;

__device__ __forceinline__ u16 f2b(float f) {  // f32 -> bf16 RNE
  u32 x = __float_as_uint(f);
  return (u16)((x + 0x7FFFu + ((x >> 16) & 1u)) >> 16);
}

__device__ __forceinline__ u32 pkbf(float a, float b) {  // pack 2xf32 -> 2xbf16
  u32 r;
  asm("v_cvt_pk_bf16_f32 %0, %1, %2" : "=v"(r) : "v"(a), "v"(b));
  return r;
}

__device__ __forceinline__ float exp2fast(float x) {
#if __has_builtin(__builtin_amdgcn_exp2f)
  return __builtin_amdgcn_exp2f(x);
#else
  return __expf(x * 0.69314718f);
#endif
}

__device__ __forceinline__ float rcpfast(float x) {
#if __has_builtin(__builtin_amdgcn_rcpf)
  return __builtin_amdgcn_rcpf(x);
#else
  return 1.f / x;
#endif
}

#define AS1(p) ((const __attribute__((address_space(1))) void*)(uintptr_t)(p))
#define AS3(p) ((__attribute__((address_space(3))) void*)(uintptr_t)(p))
#define VMCNT(n) asm volatile("s_waitcnt vmcnt(" #n ")" ::: "memory")
#define LGKM0    asm volatile("s_waitcnt lgkmcnt(0)" ::: "memory")
#define SCHED0   __builtin_amdgcn_sched_barrier(0)

// ---------------------------------------------------------------------------
// Fused prep: blocks 0..1023 convert x -> bf16 (16 elems/thread);
// blocks 1024..2047 transpose+convert the two weight matrices.
// ---------------------------------------------------------------------------
__global__ __launch_bounds__(256) void prep(
    const float* __restrict__ x, u16* __restrict__ xb,
    const float* __restrict__ wa, u16* __restrict__ wat,
    const float* __restrict__ wp, u16* __restrict__ wpt) {
  __shared__ float t[64][65];
  const int bx = blockIdx.x;
  if (bx < 1024) {
    const size_t idx = (size_t)bx * 256 + threadIdx.x;
    const float4* p = (const float4*)x + 4 * idx;
    uint4 o0, o1;
    {
      float4 a = p[0], b = p[1];
      o0.x = (u32)f2b(a.x) | ((u32)f2b(a.y) << 16);
      o0.y = (u32)f2b(a.z) | ((u32)f2b(a.w) << 16);
      o0.z = (u32)f2b(b.x) | ((u32)f2b(b.y) << 16);
      o0.w = (u32)f2b(b.z) | ((u32)f2b(b.w) << 16);
    }
    {
      float4 a = p[2], b = p[3];
      o1.x = (u32)f2b(a.x) | ((u32)f2b(a.y) << 16);
      o1.y = (u32)f2b(a.z) | ((u32)f2b(a.w) << 16);
      o1.z = (u32)f2b(b.x) | ((u32)f2b(b.y) << 16);
      o1.w = (u32)f2b(b.z) | ((u32)f2b(b.w) << 16);
    }
    ((uint4*)xb)[2 * idx] = o0;
    ((uint4*)xb)[2 * idx + 1] = o1;
    return;
  }
  const int tt = bx - 1024;
  const int bxr = tt & 63, by = tt >> 6;
  const float* w = (bxr < 48) ? wa : wp;
  u16* wt = (bxr < 48) ? wat : wpt;
  const int N = (bxr < 48) ? 3072 : 1024;
  const int bxt = (bxr < 48) ? bxr : bxr - 48;
  const int K = 1024;
  const int n0 = bxt * 64, k0 = by * 64;
  const int c = threadIdx.x & 63, r4 = threadIdx.x >> 6;
#pragma unroll
  for (int j = 0; j < 16; ++j) {
    const int r = j * 4 + r4;
    t[c][r] = w[(size_t)(k0 + r) * N + n0 + c];
  }
  __syncthreads();
#pragma unroll
  for (int j = 0; j < 16; ++j) {
    const int nr = j * 4 + r4;
    wt[(size_t)(n0 + nr) * K + k0 + c] = f2b(t[nr][c]);
  }
}

// ---------------------------------------------------------------------------
// bf16 MFMA GEMM, 128x128 tile, BK=32, 4 waves. Triple-buffered, staged
// 2 K-tiles ahead, counted-vmcnt gate BEFORE a raw barrier (T4): the newest
// 4 DMAs stay in flight across the barrier, so HBM/L2 latency is covered by
// ~2 full compute phases instead of being drained every tile.
// SCALEQ: multiply cols<1024 (the Q block of QKV) by 0.125*log2(e).
// ---------------------------------------------------------------------------
template <bool OUT_BF16, bool SCALEQ>
__global__ __launch_bounds__(256) void gemm_kmajor(
    const u16* __restrict__ A, const u16* __restrict__ Bt,
    const float* __restrict__ bias, void* __restrict__ outp,
    int M, int N, int K, int nbx) {
  __shared__ __align__(16) u16 sm[3][2][128 * 32];  // 48 KB

  const int nwg = gridDim.x;
  const int qq = nwg >> 3, rr = nwg & 7;
  const int xcd = blockIdx.x & 7, off = blockIdx.x >> 3;
  const int wgid = (xcd < rr ? xcd * (qq + 1) : rr * (qq + 1) + (xcd - rr) * qq) + off;
  const int bx = wgid % nbx, by = wgid / nbx;
  const int row0 = by * 128, col0 = bx * 128;

  const int tid = threadIdx.x;
  const int w = tid >> 6, lane = tid & 63;
  const int wrow = (w >> 1) * 64, wcol = (w & 1) * 64;

  f32x4 acc[4][4];
#pragma unroll
  for (int a = 0; a < 4; ++a)
#pragma unroll
    for (int b = 0; b < 4; ++b)
#pragma unroll
      for (int e = 0; e < 4; ++e) acc[a][b][e] = 0.f;

  const size_t Kb = (size_t)K * 2;

  auto stage = [&](int k0, int buf) {
#pragma unroll
    for (int c = 0; c < 4; ++c) {
      const int ch = w * 4 + c;
      const int i = ch & 7;
      const int rloc = i * 16 + (lane >> 2);
      const int kb = ((lane & 3) * 16) ^ ((rloc & 3) << 4);  // pre-swizzled src
      const u16* mat = (ch < 8) ? A : Bt;
      const int r0 = (ch < 8) ? row0 : col0;
      const char* src = (const char*)mat + (size_t)(r0 + rloc) * Kb + k0 * 2 + kb;
      char* dst = (char*)&sm[buf][(ch < 8) ? 0 : 1][0] + i * 1024;
      __builtin_amdgcn_global_load_lds(AS1(src), AS3(dst), 16, 0, 0);
    }
  };

  auto compute = [&](int buf) {
    bf16x8 af[4], bfr[4];
    const char* As = (const char*)&sm[buf][0][0];
    const char* Bs = (const char*)&sm[buf][1][0];
#pragma unroll
    for (int rb = 0; rb < 4; ++rb) {
      const int rl = wrow + rb * 16 + (lane & 15);
      const int kb2 = ((lane >> 4) * 16) ^ ((rl & 3) << 4);
      af[rb] = *(const bf16x8*)(As + rl * 64 + kb2);
    }
#pragma unroll
    for (int cb = 0; cb < 4; ++cb) {
      const int rl = wcol + cb * 16 + (lane & 15);
      const int kb2 = ((lane >> 4) * 16) ^ ((rl & 3) << 4);
      bfr[cb] = *(const bf16x8*)(Bs + rl * 64 + kb2);
    }
#pragma unroll
    for (int rb = 0; rb < 4; ++rb)
#pragma unroll
      for (int cb = 0; cb < 4; ++cb)
        acc[rb][cb] = __builtin_amdgcn_mfma_f32_16x16x32_bf16(
            af[rb], bfr[cb], acc[rb][cb], 0, 0, 0);
  };

  const int nt = K >> 5;  // 32
  stage(0, 0);
  SCHED0;
  stage(32, 1);
  SCHED0;
  VMCNT(4);  // stage(0) done; stage(32) in flight
  SCHED0;
  __builtin_amdgcn_s_barrier();

  int bc = 0, bn = 1, bnn = 2;
  for (int t = 0; t < nt; ++t) {
    if (t + 2 < nt) stage((t + 2) * 32, bnn);
    compute(bc);
    if (t + 1 < nt) {
      if (t + 2 < nt) { VMCNT(4); } else { VMCNT(0); }
      SCHED0;
      __builtin_amdgcn_s_barrier();
    }
    const int tmp = bc; bc = bn; bn = bnn; bnn = tmp;
  }

  const float C = 0.18033688f;  // 0.125*log2(e)
#pragma unroll
  for (int cb = 0; cb < 4; ++cb) {
    const int colg = col0 + wcol + cb * 16 + (lane & 15);
    const float bv = bias[colg];
    const bool doscale = SCALEQ && (colg < 1024);
#pragma unroll
    for (int rb = 0; rb < 4; ++rb) {
#pragma unroll
      for (int i = 0; i < 4; ++i) {
        const int rowg = row0 + wrow + rb * 16 + (lane >> 4) * 4 + i;
        float v = acc[rb][cb][i] + bv;
        if (doscale) v *= C;
        if (OUT_BF16) {
          const u32 hv = f2b(v);
          const u32 pv = (u32)__shfl_xor((int)hv, 1);
          if (!(lane & 1))
            *(u32*)((u16*)outp + (size_t)rowg * N + colg) = hv | (pv << 16);
        } else {
          ((float*)outp)[(size_t)rowg * N + colg] = v;
        }
      }
    }
  }
}

// ---------------------------------------------------------------------------
// Flash attention v3: triple-buffered K/V staged 2 tiles ahead with counted
// vmcnt gates before raw barriers (no vmcnt(0) drain in the loop). Swapped
// QK^T, P in registers, per-lane softmax state (l-reduce deferred to
// epilogue), Q pre-scaled in GEMM1. 512 paired-persistent blocks (33 tiles
// each -> balanced concurrent execution).
// ---------------------------------------------------------------------------
__global__ __launch_bounds__(256, 2) void attn_mfma3(
    const u16* __restrict__ qkvb, u16* __restrict__ yb) {
  // 3 x 8KB K + 3 x 8KB V = 48 KB
  __shared__ __align__(16) char lds[49152];

  const int bx = blockIdx.x;
  const int pr = bx >> 5;        // 0..15
  const int bh = bx & 31;
  const int bb = bh >> 4, h = bh & 15;

  const int tid = threadIdx.x;
  const int w = tid >> 6, lane = tid & 63;
  const int hh = lane >> 4, qh = lane & 15;

  const size_t rowb = 6144;  // 3072 bf16
  const char* base = (const char*)qkvb + (size_t)bb * SEQ * rowb;
  const int koffb = EMBD * 2 + h * 128;
  const int voffb = 2 * EMBD * 2 + h * 128;

  const int krow_in_chunk = lane >> 3;  // 0..7
  const int vkv = (tid & 31) * 2;
  const int vdg = tid >> 5;  // 0..7, d = vdg*8+e

  for (int half = 0; half < 2; ++half) {
    const int qt = half ? pr : 31 - pr;
    const int q_abs = qt * 64 + w * 16 + qh;
    const int qloc = w * 16 + qh;

    // Q B-fragments (pre-scaled by 0.125*log2e in GEMM1)
    const char* qp = base + (size_t)q_abs * rowb + h * 128 + hh * 16;
    const bf16x8 qf0 = *(const bf16x8*)qp;
    const bf16x8 qf1 = *(const bf16x8*)(qp + 64);
    SCHED0;

    float m2 = -1e30f, l = 0.f;
    f32x4 of[4];
#pragma unroll
    for (int db = 0; db < 4; ++db)
#pragma unroll
      for (int e = 0; e < 4; ++e) of[db][e] = 0.f;

    // helpers -------------------------------------------------------------
    auto issueV = [&](int kt, uint4& a, uint4& b) {
      const char* vp = base + (size_t)(kt * 64 + vkv) * rowb + voffb + vdg * 16;
      a = *(const uint4*)vp;
      b = *(const uint4*)(vp + rowb);
    };
    auto issueK = [&](int kt, int buf) {
#pragma unroll
      for (int cc = 0; cc < 2; ++cc) {
        const int i = w * 2 + cc;
        const int kvl = i * 8 + krow_in_chunk;
        const int gs = (lane & 7) ^ ((i & 3) | ((krow_in_chunk & 1) << 2));
        const char* src = base + (size_t)(kt * 64 + kvl) * rowb + koffb + gs * 16;
        __builtin_amdgcn_global_load_lds(AS1(src),
                                         AS3(lds + buf * 8192 + i * 1024), 16, 0, 0);
      }
    };
    auto writeV = [&](const uint4& a, const uint4& b, int buf) {
      union { uint4 q; u16 s[8]; } ua, ub;
      ua.q = a; ub.q = b;
      u32* vt = (u32*)(lds + 24576 + buf * 8192);
#pragma unroll
      for (int e = 0; e < 8; ++e) {
        const int d = vdg * 8 + e;
        vt[d * 32 + ((vkv >> 1) ^ ((d & 7) << 2))] =
            (u32)ua.s[e] | ((u32)ub.s[e] << 16);
      }
    };

    // ---- prologue: V0,K0 (buf0) + V1,K1 (buf1); gate-before-barrier ----
    uint4 v0a, v0b, vpa, vpb, vna = {}, vnb = {};
    issueV(0, v0a, v0b);
    SCHED0;
    issueK(0, 0);
    SCHED0;
    issueV(1, vpa, vpb);   // tile-1 rows always exist (SEQ=2048)
    SCHED0;
    issueK(1, 1);
    SCHED0;
    VMCNT(6);              // V0 landed (K0,V1,K1 may be in flight)
    SCHED0;
    writeV(v0a, v0b, 0);
    VMCNT(4);              // K0 landed pre-barrier
    LGKM0;
    SCHED0;
    __builtin_amdgcn_s_barrier();

    int bc = 0, bn = 1, bnn = 2;
    for (int kt = 0; kt <= qt; ++kt) {
      const char* ksb = lds + bc * 8192;
      const char* vtb = lds + 24576 + bc * 8192;

      const bool pref2 = (kt + 2 <= qt);
      if (pref2) {
        issueV(kt + 2, vna, vnb);
        issueK(kt + 2, bnn);
      }

      // ---- S^T = K Q^T (A rows permuted to match PV A-frag kv-slots) ----
      f32x4 st[4];
      __builtin_amdgcn_s_setprio(1);
#pragma unroll
      for (int rb = 0; rb < 4; ++rb) {
#pragma unroll
        for (int e = 0; e < 4; ++e) st[rb][e] = 0.f;
        const int kv = 32 * (rb >> 1) + 8 * ((lane >> 2) & 3) + 4 * (rb & 1) +
                       (lane & 3);
        const int f = ((kv >> 3) & 3) | ((kv & 1) << 2);
        const char* rp = ksb + kv * 128;
        const bf16x8 k0 = *(const bf16x8*)(rp + ((hh * 16) ^ (f << 4)));
        const bf16x8 k1 = *(const bf16x8*)(rp + ((64 + hh * 16) ^ (f << 4)));
        st[rb] = __builtin_amdgcn_mfma_f32_16x16x32_bf16(k0, qf0, st[rb], 0, 0, 0);
        st[rb] = __builtin_amdgcn_mfma_f32_16x16x32_bf16(k1, qf1, st[rb], 0, 0, 0);
      }
      __builtin_amdgcn_s_setprio(0);

      // ---- softmax (exp2 domain; Q pre-scaled) ----
      float pmax = -3.0e38f;
      if (kt == qt) {
#pragma unroll
        for (int rb = 0; rb < 4; ++rb) {
          const int kvb = 32 * (rb >> 1) + 8 * hh + 4 * (rb & 1);
#pragma unroll
          for (int i = 0; i < 4; ++i) {
            float v = st[rb][i];
            if (kvb + i > qloc) v = -3.0e38f;
            st[rb][i] = v;
            pmax = fmaxf(pmax, v);
          }
        }
      } else {
#pragma unroll
        for (int rb = 0; rb < 4; ++rb)
#pragma unroll
          for (int i = 0; i < 4; ++i) pmax = fmaxf(pmax, st[rb][i]);
      }
      pmax = fmaxf(pmax, __shfl_xor(pmax, 16));
      pmax = fmaxf(pmax, __shfl_xor(pmax, 32));

      if (__any(pmax > m2 + 5.f)) {  // defer-max: rescale rarely
        const float mn = fmaxf(m2, pmax);
        const float al = exp2fast(m2 - mn);
        m2 = mn;
        l *= al;
#pragma unroll
        for (int db = 0; db < 4; ++db)
#pragma unroll
          for (int e = 0; e < 4; ++e) of[db][e] *= al;
      }

#pragma unroll
      for (int rb = 0; rb < 4; ++rb)
#pragma unroll
        for (int i = 0; i < 4; ++i) {
          const float p = exp2fast(st[rb][i] - m2);
          st[rb][i] = p;
          l += p;  // per-lane partial; reduced in epilogue
        }

      union { u32 wd[4]; bf16x8 v; } pf0, pf1;
      pf0.wd[0] = pkbf(st[0][0], st[0][1]);
      pf0.wd[1] = pkbf(st[0][2], st[0][3]);
      pf0.wd[2] = pkbf(st[1][0], st[1][1]);
      pf0.wd[3] = pkbf(st[1][2], st[1][3]);
      pf1.wd[0] = pkbf(st[2][0], st[2][1]);
      pf1.wd[1] = pkbf(st[2][2], st[2][3]);
      pf1.wd[2] = pkbf(st[3][0], st[3][1]);
      pf1.wd[3] = pkbf(st[3][2], st[3][3]);

      // ---- O^T += V^T P^T ----
      __builtin_amdgcn_s_setprio(1);
#pragma unroll
      for (int db = 0; db < 4; ++db) {
        const int d = db * 16 + qh;
        const int g2 = d & 7;
        const char* rp = vtb + d * 128;
        const bf16x8 v0 = *(const bf16x8*)(rp + ((hh * 16) ^ (g2 << 4)));
        const bf16x8 v1 = *(const bf16x8*)(rp + ((64 + hh * 16) ^ (g2 << 4)));
        of[db] = __builtin_amdgcn_mfma_f32_16x16x32_bf16(v0, pf0.v, of[db], 0, 0, 0);
        of[db] = __builtin_amdgcn_mfma_f32_16x16x32_bf16(v1, pf1.v, of[db], 0, 0, 0);
      }
      __builtin_amdgcn_s_setprio(0);

      if (kt < qt) {
        // gate BEFORE barrier: tile kt+1's V loads + K DMA landed;
        // tile kt+2's 4 vmem ops stay in flight across the barrier.
        if (pref2) { VMCNT(4); } else { VMCNT(0); }
        SCHED0;
        writeV(vpa, vpb, bn);
        LGKM0;
        SCHED0;
        __builtin_amdgcn_s_barrier();
        vpa = vna; vpb = vnb;
      }
      const int tmp = bc; bc = bn; bn = bnn; bnn = tmp;
    }

    // ---- epilogue: reduce l across the 4 row-lanes, write y ----
    l += __shfl_xor(l, 16);
    l += __shfl_xor(l, 32);
    const float inv = rcpfast(l);
    u16* yrow = yb + (size_t)(bb * SEQ + q_abs) * EMBD + h * 64;
#pragma unroll
    for (int db = 0; db < 4; ++db) {
      const u32 w0 = pkbf(of[db][0] * inv, of[db][1] * inv);
      const u32 w1 = pkbf(of[db][2] * inv, of[db][3] * inv);
      *(u32*)(yrow + db * 16 + 4 * hh) = w0;
      *(u32*)(yrow + db * 16 + 4 * hh + 2) = w1;
    }
    __syncthreads();  // full drain between halves (also clears stale DMAs)
  }
}

// ---------------------------------------------------------------------------
extern "C" void kernel_launch(void* const* d_in, const int* in_sizes, int n_in,
                              void* d_out, int out_size, void* d_ws,
                              size_t ws_size, hipStream_t stream) {
  const float* x      = (const float*)d_in[0];
  const float* w_attn = (const float*)d_in[1];
  const float* b_attn = (const float*)d_in[2];
  const float* w_proj = (const float*)d_in[3];
  const float* b_proj = (const float*)d_in[4];
  float* out = (float*)d_out;

  u16* xb   = (u16*)d_ws;                          //  8 MB  [4096][1024]
  u16* wat  = xb + (size_t)M_ROWS * EMBD;          //  6 MB  [3072][1024]
  u16* wpt  = wat + (size_t)3 * EMBD * EMBD;       //  2 MB  [1024][1024]
  u16* qkvb = wpt + (size_t)EMBD * EMBD;           // 24 MB  [4096][3072]
  u16* yb   = qkvb + (size_t)M_ROWS * 3 * EMBD;    //  8 MB  [4096][1024]

  prep<<<2048, 256, 0, stream>>>(x, xb, w_attn, wat, w_proj, wpt);

  gemm_kmajor<true, true><<<768, 256, 0, stream>>>(
      xb, wat, b_attn, qkvb, M_ROWS, 3 * EMBD, EMBD, 24);

  attn_mfma3<<<512, 256, 0, stream>>>(qkvb, yb);

  gemm_kmajor<false, false><<<256, 256, 0, stream>>>(
      yb, wpt, b_proj, out, M_ROWS, EMBD, EMBD, 8);
}

// Round 10
// 182.980 us; speedup vs baseline: 1.0111x; 1.0111x over previous
//
#include <hip/hip_runtime.h>
#include <stdint.h>

// B=2, T=2048, C=1024, H=16, D=64
#define SEQ   2048
#define EMBD  1024
#define M_ROWS 4096

typedef unsigned short u16;
typedef unsigned int u32;
typedef __attribute__((ext_vector_type(8))) short bf16x8;
typedef __attribute__((ext_vector_type(4))) float f32x4;

__device__ __forceinline__ u16 f2b(float f) {  // f32 -> bf16 RNE
  u32 x = __float_as_uint(f);
  return (u16)((x + 0x7FFFu + ((x >> 16) & 1u)) >> 16);
}

__device__ __forceinline__ u32 pkbf(float a, float b) {  // pack 2xf32 -> 2xbf16
  u32 r;
  asm("v_cvt_pk_bf16_f32 %0, %1, %2" : "=v"(r) : "v"(a), "v"(b));
  return r;
}

__device__ __forceinline__ float exp2fast(float x) {
#if __has_builtin(__builtin_amdgcn_exp2f)
  return __builtin_amdgcn_exp2f(x);
#else
  return __expf(x * 0.69314718f);
#endif
}

__device__ __forceinline__ float rcpfast(float x) {
#if __has_builtin(__builtin_amdgcn_rcpf)
  return __builtin_amdgcn_rcpf(x);
#else
  return 1.f / x;
#endif
}

#define AS1(p) ((const __attribute__((address_space(1))) void*)(uintptr_t)(p))
#define AS3(p) ((__attribute__((address_space(3))) void*)(uintptr_t)(p))
#define VMCNT(n) asm volatile("s_waitcnt vmcnt(" #n ")" ::: "memory")
#define LGKM0    asm volatile("s_waitcnt lgkmcnt(0)" ::: "memory")
#define SCHED0   __builtin_amdgcn_sched_barrier(0)

// ---------------------------------------------------------------------------
// Fused prep: blocks 0..1023 convert x -> bf16 (16 elems/thread);
// blocks 1024..2047 transpose+convert the two weight matrices.
// ---------------------------------------------------------------------------
__global__ __launch_bounds__(256) void prep(
    const float* __restrict__ x, u16* __restrict__ xb,
    const float* __restrict__ wa, u16* __restrict__ wat,
    const float* __restrict__ wp, u16* __restrict__ wpt) {
  __shared__ float t[64][65];
  const int bx = blockIdx.x;
  if (bx < 1024) {
    const size_t idx = (size_t)bx * 256 + threadIdx.x;
    const float4* p = (const float4*)x + 4 * idx;
    uint4 o0, o1;
    {
      float4 a = p[0], b = p[1];
      o0.x = (u32)f2b(a.x) | ((u32)f2b(a.y) << 16);
      o0.y = (u32)f2b(a.z) | ((u32)f2b(a.w) << 16);
      o0.z = (u32)f2b(b.x) | ((u32)f2b(b.y) << 16);
      o0.w = (u32)f2b(b.z) | ((u32)f2b(b.w) << 16);
    }
    {
      float4 a = p[2], b = p[3];
      o1.x = (u32)f2b(a.x) | ((u32)f2b(a.y) << 16);
      o1.y = (u32)f2b(a.z) | ((u32)f2b(a.w) << 16);
      o1.z = (u32)f2b(b.x) | ((u32)f2b(b.y) << 16);
      o1.w = (u32)f2b(b.z) | ((u32)f2b(b.w) << 16);
    }
    ((uint4*)xb)[2 * idx] = o0;
    ((uint4*)xb)[2 * idx + 1] = o1;
    return;
  }
  const int tt = bx - 1024;
  const int bxr = tt & 63, by = tt >> 6;
  const float* w = (bxr < 48) ? wa : wp;
  u16* wt = (bxr < 48) ? wat : wpt;
  const int N = (bxr < 48) ? 3072 : 1024;
  const int bxt = (bxr < 48) ? bxr : bxr - 48;
  const int K = 1024;
  const int n0 = bxt * 64, k0 = by * 64;
  const int c = threadIdx.x & 63, r4 = threadIdx.x >> 6;
#pragma unroll
  for (int j = 0; j < 16; ++j) {
    const int r = j * 4 + r4;
    t[c][r] = w[(size_t)(k0 + r) * N + n0 + c];
  }
  __syncthreads();
#pragma unroll
  for (int j = 0; j < 16; ++j) {
    const int nr = j * 4 + r4;
    wt[(size_t)(n0 + nr) * K + k0 + c] = f2b(t[nr][c]);
  }
}

// ---------------------------------------------------------------------------
// bf16 MFMA GEMM, 128x128 tile, BK=32, 4 waves. Triple-buffered, staged
// 2 K-tiles ahead, counted-vmcnt gate BEFORE a raw barrier (T4), + T5
// setprio around the MFMA cluster. (Verified passing in rounds 5/6.)
// ---------------------------------------------------------------------------
template <bool OUT_BF16, bool SCALEQ>
__global__ __launch_bounds__(256) void gemm_kmajor(
    const u16* __restrict__ A, const u16* __restrict__ Bt,
    const float* __restrict__ bias, void* __restrict__ outp,
    int M, int N, int K, int nbx) {
  __shared__ __align__(16) u16 sm[3][2][128 * 32];  // 48 KB

  const int nwg = gridDim.x;
  const int qq = nwg >> 3, rr = nwg & 7;
  const int xcd = blockIdx.x & 7, off = blockIdx.x >> 3;
  const int wgid = (xcd < rr ? xcd * (qq + 1) : rr * (qq + 1) + (xcd - rr) * qq) + off;
  const int bx = wgid % nbx, by = wgid / nbx;
  const int row0 = by * 128, col0 = bx * 128;

  const int tid = threadIdx.x;
  const int w = tid >> 6, lane = tid & 63;
  const int wrow = (w >> 1) * 64, wcol = (w & 1) * 64;

  f32x4 acc[4][4];
#pragma unroll
  for (int a = 0; a < 4; ++a)
#pragma unroll
    for (int b = 0; b < 4; ++b)
#pragma unroll
      for (int e = 0; e < 4; ++e) acc[a][b][e] = 0.f;

  const size_t Kb = (size_t)K * 2;

  auto stage = [&](int k0, int buf) {
#pragma unroll
    for (int c = 0; c < 4; ++c) {
      const int ch = w * 4 + c;
      const int i = ch & 7;
      const int rloc = i * 16 + (lane >> 2);
      const int kb = ((lane & 3) * 16) ^ ((rloc & 3) << 4);  // pre-swizzled src
      const u16* mat = (ch < 8) ? A : Bt;
      const int r0 = (ch < 8) ? row0 : col0;
      const char* src = (const char*)mat + (size_t)(r0 + rloc) * Kb + k0 * 2 + kb;
      char* dst = (char*)&sm[buf][(ch < 8) ? 0 : 1][0] + i * 1024;
      __builtin_amdgcn_global_load_lds(AS1(src), AS3(dst), 16, 0, 0);
    }
  };

  auto compute = [&](int buf) {
    bf16x8 af[4], bfr[4];
    const char* As = (const char*)&sm[buf][0][0];
    const char* Bs = (const char*)&sm[buf][1][0];
#pragma unroll
    for (int rb = 0; rb < 4; ++rb) {
      const int rl = wrow + rb * 16 + (lane & 15);
      const int kb2 = ((lane >> 4) * 16) ^ ((rl & 3) << 4);
      af[rb] = *(const bf16x8*)(As + rl * 64 + kb2);
    }
#pragma unroll
    for (int cb = 0; cb < 4; ++cb) {
      const int rl = wcol + cb * 16 + (lane & 15);
      const int kb2 = ((lane >> 4) * 16) ^ ((rl & 3) << 4);
      bfr[cb] = *(const bf16x8*)(Bs + rl * 64 + kb2);
    }
    __builtin_amdgcn_s_setprio(1);
#pragma unroll
    for (int rb = 0; rb < 4; ++rb)
#pragma unroll
      for (int cb = 0; cb < 4; ++cb)
        acc[rb][cb] = __builtin_amdgcn_mfma_f32_16x16x32_bf16(
            af[rb], bfr[cb], acc[rb][cb], 0, 0, 0);
    __builtin_amdgcn_s_setprio(0);
  };

  const int nt = K >> 5;  // 32
  stage(0, 0);
  SCHED0;
  stage(32, 1);
  SCHED0;
  VMCNT(4);  // stage(0) done; stage(32) in flight
  SCHED0;
  __builtin_amdgcn_s_barrier();

  int bc = 0, bn = 1, bnn = 2;
  for (int t = 0; t < nt; ++t) {
    if (t + 2 < nt) stage((t + 2) * 32, bnn);
    compute(bc);
    if (t + 1 < nt) {
      if (t + 2 < nt) { VMCNT(4); } else { VMCNT(0); }
      SCHED0;
      __builtin_amdgcn_s_barrier();
    }
    const int tmp = bc; bc = bn; bn = bnn; bnn = tmp;
  }

  const float C = 0.18033688f;  // 0.125*log2(e)
#pragma unroll
  for (int cb = 0; cb < 4; ++cb) {
    const int colg = col0 + wcol + cb * 16 + (lane & 15);
    const float bv = bias[colg];
    const bool doscale = SCALEQ && (colg < 1024);
#pragma unroll
    for (int rb = 0; rb < 4; ++rb) {
#pragma unroll
      for (int i = 0; i < 4; ++i) {
        const int rowg = row0 + wrow + rb * 16 + (lane >> 4) * 4 + i;
        float v = acc[rb][cb][i] + bv;
        if (doscale) v *= C;
        if (OUT_BF16) {
          const u32 hv = f2b(v);
          const u32 pv = (u32)__shfl_xor((int)hv, 1);
          if (!(lane & 1))
            *(u32*)((u16*)outp + (size_t)rowg * N + colg) = hv | (pv << 16);
        } else {
          ((float*)outp)[(size_t)rowg * N + colg] = v;
        }
      }
    }
  }
}

// ---------------------------------------------------------------------------
// Flash attention (verified round-4 structure): one 64-row q-tile per block,
// 1024 blocks (4/CU, 16 waves/CU), XCD-local head map + boustrophedon qt.
// Swapped QK^T with permuted A-rows so P stays in registers; per-lane
// softmax; dbuf K/V, 1 barrier/tile. Micro-opts ported from the verified
// round-5 kernel: Q pre-scaled in GEMM1 (no per-tile scale mul) and
// l-reduction deferred to the epilogue (no per-tile shuffles).
// ---------------------------------------------------------------------------
__global__ __launch_bounds__(256, 4) void attn_mfma2(
    const u16* __restrict__ qkvb, u16* __restrict__ yb) {
  __shared__ __align__(16) char lds[32768];

  const int bx = blockIdx.x;
  const int xcd = bx & 7, g = bx >> 3;
  const int j = g >> 5, r = g & 31;
  const int bh = xcd * 4 + j;               // head-batch index, 4 per XCD
  const int qt = (j & 1) ? r : 31 - r;      // boustrophedon: CU work ~const
  const int bb = bh >> 4, h = bh & 15;

  const int tid = threadIdx.x;
  const int w = tid >> 6, lane = tid & 63;
  const int hh = lane >> 4, qh = lane & 15;

  const size_t rowb = 6144;  // 3072 bf16
  const char* base = (const char*)qkvb + (size_t)bb * SEQ * rowb;
  const int koffb = EMBD * 2 + h * 128;
  const int voffb = 2 * EMBD * 2 + h * 128;

  const int krow_in_chunk = lane >> 3;  // 0..7
  const int vkv = (tid & 31) * 2;
  const int vdg = tid >> 5;  // 0..7, d = vdg*8+e

  const int q_abs = qt * 64 + w * 16 + qh;
  const int qloc = w * 16 + qh;

  // Q B-fragments (pre-scaled by 0.125*log2e in GEMM1)
  const char* qp = base + (size_t)q_abs * rowb + h * 128 + hh * 16;
  const bf16x8 qf0 = *(const bf16x8*)qp;
  const bf16x8 qf1 = *(const bf16x8*)(qp + 64);

  float m2 = -1e30f, l = 0.f;
  f32x4 of[4];
#pragma unroll
  for (int db = 0; db < 4; ++db)
#pragma unroll
    for (int e = 0; e < 4; ++e) of[db][e] = 0.f;

  // ---- prologue: stage tile kt=0 into buf 0 ----
  {
#pragma unroll
    for (int cc = 0; cc < 2; ++cc) {
      const int i = w * 2 + cc;
      const int kvl = i * 8 + krow_in_chunk;
      const int gs = (lane & 7) ^ ((i & 3) | ((krow_in_chunk & 1) << 2));
      const char* src = base + (size_t)kvl * rowb + koffb + gs * 16;
      __builtin_amdgcn_global_load_lds(AS1(src), AS3(lds + i * 1024), 16, 0, 0);
    }
    const char* vp = base + (size_t)vkv * rowb + voffb + vdg * 16;
    uint4 va = *(const uint4*)vp;
    uint4 vb = *(const uint4*)(vp + rowb);
    union { uint4 q; u16 s[8]; } ua, ub;
    ua.q = va; ub.q = vb;
    u32* vt = (u32*)(lds + 16384);
#pragma unroll
    for (int e = 0; e < 8; ++e) {
      const int d = vdg * 8 + e;
      vt[d * 32 + ((vkv >> 1) ^ ((d & 7) << 2))] =
          (u32)ua.s[e] | ((u32)ub.s[e] << 16);
    }
  }
  __syncthreads();

  for (int kt = 0; kt <= qt; ++kt) {
    const int cur = kt & 1;
    const char* ksb = lds + cur * 8192;
    const char* vtb = lds + 16384 + cur * 8192;

    // ---- prefetch tile kt+1 (issue early) ----
    uint4 va, vb;
    const bool pref = (kt < qt);
    if (pref) {
#pragma unroll
      for (int cc = 0; cc < 2; ++cc) {
        const int i = w * 2 + cc;
        const int kvl = i * 8 + krow_in_chunk;
        const int gs = (lane & 7) ^ ((i & 3) | ((krow_in_chunk & 1) << 2));
        const char* src =
            base + (size_t)((kt + 1) * 64 + kvl) * rowb + koffb + gs * 16;
        __builtin_amdgcn_global_load_lds(
            AS1(src), AS3(lds + (cur ^ 1) * 8192 + i * 1024), 16, 0, 0);
      }
      const char* vp =
          base + (size_t)((kt + 1) * 64 + vkv) * rowb + voffb + vdg * 16;
      va = *(const uint4*)vp;
      vb = *(const uint4*)(vp + rowb);
    }

    // ---- S^T = K Q^T (A rows permuted so output kv-slots match PV A-frag) ----
    f32x4 st[4];
    __builtin_amdgcn_s_setprio(1);
#pragma unroll
    for (int rb = 0; rb < 4; ++rb) {
#pragma unroll
      for (int e = 0; e < 4; ++e) st[rb][e] = 0.f;
      const int kv = 32 * (rb >> 1) + 8 * ((lane >> 2) & 3) + 4 * (rb & 1) +
                     (lane & 3);
      const int f = ((kv >> 3) & 3) | ((kv & 1) << 2);
      const char* rp = ksb + kv * 128;
      const bf16x8 k0 = *(const bf16x8*)(rp + ((hh * 16) ^ (f << 4)));
      const bf16x8 k1 = *(const bf16x8*)(rp + ((64 + hh * 16) ^ (f << 4)));
      st[rb] = __builtin_amdgcn_mfma_f32_16x16x32_bf16(k0, qf0, st[rb], 0, 0, 0);
      st[rb] = __builtin_amdgcn_mfma_f32_16x16x32_bf16(k1, qf1, st[rb], 0, 0, 0);
    }
    __builtin_amdgcn_s_setprio(0);

    // ---- softmax (exp2 domain; Q pre-scaled) ----
    // lane's value (rb,i) is kv = 32*(rb>>1) + 8*hh + 4*(rb&1) + i
    float pmax = -3.0e38f;
    if (kt == qt) {
#pragma unroll
      for (int rb = 0; rb < 4; ++rb) {
        const int kvb = 32 * (rb >> 1) + 8 * hh + 4 * (rb & 1);
#pragma unroll
        for (int i = 0; i < 4; ++i) {
          if (kvb + i > qloc) st[rb][i] = -3.0e38f;
          pmax = fmaxf(pmax, st[rb][i]);
        }
      }
    } else {
#pragma unroll
      for (int rb = 0; rb < 4; ++rb)
#pragma unroll
        for (int i = 0; i < 4; ++i) pmax = fmaxf(pmax, st[rb][i]);
    }
    pmax = fmaxf(pmax, __shfl_xor(pmax, 16));
    pmax = fmaxf(pmax, __shfl_xor(pmax, 32));

    if (__any(pmax > m2 + 5.f)) {  // defer-max: rescale rarely
      const float mn = fmaxf(m2, pmax);
      const float al = exp2fast(m2 - mn);
      m2 = mn;
      l *= al;
#pragma unroll
      for (int db = 0; db < 4; ++db)
#pragma unroll
        for (int e = 0; e < 4; ++e) of[db][e] *= al;
    }

#pragma unroll
    for (int rb = 0; rb < 4; ++rb)
#pragma unroll
      for (int i = 0; i < 4; ++i) {
        const float p = exp2fast(st[rb][i] - m2);
        st[rb][i] = p;
        l += p;  // per-lane partial; reduced in epilogue
      }

    union { u32 wd[4]; bf16x8 v; } pf0, pf1;
    pf0.wd[0] = pkbf(st[0][0], st[0][1]);
    pf0.wd[1] = pkbf(st[0][2], st[0][3]);
    pf0.wd[2] = pkbf(st[1][0], st[1][1]);
    pf0.wd[3] = pkbf(st[1][2], st[1][3]);
    pf1.wd[0] = pkbf(st[2][0], st[2][1]);
    pf1.wd[1] = pkbf(st[2][2], st[2][3]);
    pf1.wd[2] = pkbf(st[3][0], st[3][1]);
    pf1.wd[3] = pkbf(st[3][2], st[3][3]);

    // ---- O^T += V^T P^T ----
    __builtin_amdgcn_s_setprio(1);
#pragma unroll
    for (int db = 0; db < 4; ++db) {
      const int d = db * 16 + qh;
      const int g2 = d & 7;
      const char* rp = vtb + d * 128;
      const bf16x8 v0 = *(const bf16x8*)(rp + ((hh * 16) ^ (g2 << 4)));
      const bf16x8 v1 = *(const bf16x8*)(rp + ((64 + hh * 16) ^ (g2 << 4)));
      of[db] = __builtin_amdgcn_mfma_f32_16x16x32_bf16(v0, pf0.v, of[db], 0, 0, 0);
      of[db] = __builtin_amdgcn_mfma_f32_16x16x32_bf16(v1, pf1.v, of[db], 0, 0, 0);
    }
    __builtin_amdgcn_s_setprio(0);

    // ---- write prefetched V into buf cur^1 ----
    if (pref) {
      union { uint4 q; u16 s[8]; } ua, ub;
      ua.q = va; ub.q = vb;
      u32* vt = (u32*)(lds + 16384 + (cur ^ 1) * 8192);
#pragma unroll
      for (int e = 0; e < 8; ++e) {
        const int d = vdg * 8 + e;
        vt[d * 32 + ((vkv >> 1) ^ ((d & 7) << 2))] =
            (u32)ua.s[e] | ((u32)ub.s[e] << 16);
      }
    }
    __syncthreads();
  }

  // ---- epilogue: reduce l across the 4 row-lanes, write y ----
  l += __shfl_xor(l, 16);
  l += __shfl_xor(l, 32);
  const float inv = rcpfast(l);
  u16* yrow = yb + (size_t)(bb * SEQ + q_abs) * EMBD + h * 64;
#pragma unroll
  for (int db = 0; db < 4; ++db) {
    const u32 w0 = pkbf(of[db][0] * inv, of[db][1] * inv);
    const u32 w1 = pkbf(of[db][2] * inv, of[db][3] * inv);
    *(u32*)(yrow + db * 16 + 4 * hh) = w0;
    *(u32*)(yrow + db * 16 + 4 * hh + 2) = w1;
  }
}

// ---------------------------------------------------------------------------
extern "C" void kernel_launch(void* const* d_in, const int* in_sizes, int n_in,
                              void* d_out, int out_size, void* d_ws,
                              size_t ws_size, hipStream_t stream) {
  const float* x      = (const float*)d_in[0];
  const float* w_attn = (const float*)d_in[1];
  const float* b_attn = (const float*)d_in[2];
  const float* w_proj = (const float*)d_in[3];
  const float* b_proj = (const float*)d_in[4];
  float* out = (float*)d_out;

  u16* xb   = (u16*)d_ws;                          //  8 MB  [4096][1024]
  u16* wat  = xb + (size_t)M_ROWS * EMBD;          //  6 MB  [3072][1024]
  u16* wpt  = wat + (size_t)3 * EMBD * EMBD;       //  2 MB  [1024][1024]
  u16* qkvb = wpt + (size_t)EMBD * EMBD;           // 24 MB  [4096][3072]
  u16* yb   = qkvb + (size_t)M_ROWS * 3 * EMBD;    //  8 MB  [4096][1024]

  prep<<<2048, 256, 0, stream>>>(x, xb, w_attn, wat, w_proj, wpt);

  gemm_kmajor<true, true><<<768, 256, 0, stream>>>(
      xb, wat, b_attn, qkvb, M_ROWS, 3 * EMBD, EMBD, 24);

  attn_mfma2<<<1024, 256, 0, stream>>>(qkvb, yb);

  gemm_kmajor<false, false><<<256, 256, 0, stream>>>(
      yb, wpt, b_proj, out, M_ROWS, EMBD, EMBD, 8);
}